// Round 14
// baseline (166.414 us; speedup 1.0000x reference)
//
#include <hip/hip_runtime.h>

#define IN_CH    16
#define OUT_CH   64
#define SET_LEN  64
#define BB       8
#define HH       56
#define WW       56

#define TILEROWS 8              // output rows per block (56 = 7*8)
#define NTILES   7
#define LDSROWS  (TILEROWS + 2) // staged rows incl. halo
#define LROW     56             // exactly the data columns; 224B row stride
#define LDS_XN   (IN_CH * LDSROWS * LROW)   // 8960 floats = 35840 B
#define NVEC     (IN_CH * LDSROWS * 14)     // 2240 float4 transfers

// ws layout: [0,2048): packed channel words (8 u32/oc); [2048,+192K): weight records
#define WS_CW_OFF 0
#define WS_W_OFF  2048
#define WS_NEEDED (WS_W_OFF + OUT_CH * SET_LEN * 12 * 4)   // 198656 B

typedef float f32x2 __attribute__((ext_vector_type(2)));
typedef float f32x4 __attribute__((ext_vector_type(4)));

static __device__ __forceinline__ f32x2 splat2(float s) { return (f32x2){s, s}; }

// ---- packed-fp32 VOP3P helpers: 64b VGPR-pair half broadcast to both lanes ----
static __device__ __forceinline__ f32x2 pk_mul_vlo(unsigned long long wp, f32x2 b) {
    f32x2 d;
    asm("v_pk_mul_f32 %0, %1, %2 op_sel:[0,0] op_sel_hi:[0,1]"
        : "=v"(d) : "v"(wp), "v"(b));
    return d;
}
static __device__ __forceinline__ f32x2 pk_mul_vhi(unsigned long long wp, f32x2 b) {
    f32x2 d;
    asm("v_pk_mul_f32 %0, %1, %2 op_sel:[1,0] op_sel_hi:[1,1]"
        : "=v"(d) : "v"(wp), "v"(b));
    return d;
}
static __device__ __forceinline__ f32x2 pk_fma_vlo(unsigned long long wp, f32x2 b, f32x2 c) {
    f32x2 d;
    asm("v_pk_fma_f32 %0, %1, %2, %3 op_sel:[0,0,0] op_sel_hi:[0,1,1]"
        : "=v"(d) : "v"(wp), "v"(b), "v"(c));
    return d;
}
static __device__ __forceinline__ f32x2 pk_fma_vhi(unsigned long long wp, f32x2 b, f32x2 c) {
    f32x2 d;
    asm("v_pk_fma_f32 %0, %1, %2, %3 op_sel:[1,0,0] op_sel_hi:[1,1,1]"
        : "=v"(d) : "v"(wp), "v"(b), "v"(c));
    return d;
}
static __device__ __forceinline__ f32x2 pk_add_vv(f32x2 a, f32x2 b) {
    f32x2 d;
    asm("v_pk_add_f32 %0, %1, %2 op_sel:[0,0] op_sel_hi:[1,1]"
        : "=v"(d) : "v"(a), "v"(b));
    return d;
}
static __device__ __forceinline__ f32x2 pk_add_vhi(unsigned long long wp, f32x2 b) {
    f32x2 d;
    asm("v_pk_add_f32 %0, %1, %2 op_sel:[1,0] op_sel_hi:[1,1]"
        : "=v"(d) : "v"(wp), "v"(b));
    return d;
}

// ---------------- pre-kernel: per-oc counting sort + weight gather + chan words ----
// record per entry (12 floats, 48B): w0..w8, bias, chan(bits), pad
__global__ __launch_bounds__(64)
void rptn_presort(const float* __restrict__ w, const float* __restrict__ bias,
                  const int* __restrict__ idx, unsigned* __restrict__ ws_cw,
                  float* __restrict__ ws_w) {
    const int oc = blockIdx.x;
    const int t  = threadIdx.x;
    __shared__ int cnt[IN_CH], pos[IN_CH], eord[SET_LEN];

    if (t < IN_CH) cnt[t] = 0;
    __syncthreads();
    const int e = idx[oc * SET_LEN + t];
    const int c = e >> 8;
    atomicAdd(&cnt[c], 1);
    __syncthreads();
    if (t == 0) {
        int run = 0;
        for (int i = 0; i < IN_CH; ++i) { pos[i] = run; run += cnt[i]; }
    }
    __syncthreads();
    const int p = atomicAdd(&pos[c], 1);
    eord[p] = e;
    __syncthreads();

    const int    es  = eord[t];
    float*       dst = ws_w + ((size_t)oc * SET_LEN + t) * 12;
    const float* src = w + es * 9;
    #pragma unroll
    for (int i = 0; i < 9; ++i) dst[i] = src[i];
    dst[9]  = bias[es];
    dst[10] = __int_as_float(es >> 8);
    dst[11] = 0.0f;

    if (t < 8) {                     // pack 8 sorted channel ids per u32
        unsigned wd = 0;
        #pragma unroll
        for (int j = 0; j < 8; ++j)
            wd |= ((unsigned)(eord[t * 8 + j] >> 8)) << (4 * j);
        ws_cw[oc * 8 + t] = wd;
    }
}

// ---------------- main fused kernel (VMEM weights + SALU channel ids) ----------------
__global__ __launch_bounds__(256, 2)
void rptn_fused_kernel(const float* __restrict__ x,
                       const unsigned* __restrict__ ws_cw,
                       const float* __restrict__ ws_w,
                       float*       __restrict__ out) {
    const int oc   = blockIdx.x;   // fastest-varying -> x tile reused across oc in L2
    const int tile = blockIdx.y;
    const int b    = blockIdx.z;
    const int tid  = threadIdx.x;
    const int tx   = tid & 63;
    const int grp  = __builtin_amdgcn_readfirstlane(tid >> 6); // wave-uniform

    __shared__ float s_x[LDS_XN];

    // ---- stage x tile: aligned vec4 loads + vec4 LDS writes, fully pipelined ----
    const int r0 = tile * TILEROWS;
    const float* xb = x + (size_t)b * IN_CH * HH * WW;
    #pragma unroll
    for (int it = 0; it < 9; ++it) {
        const int v = tid + it * 256;
        if (it < 8 || v < NVEC) {                  // last round: tid<192
            const int c   = v / (LDSROWS * 14);
            const int rem = v - c * (LDSROWS * 14);
            const int r   = rem / 14;
            const int q   = rem - r * 14;
            const int gr  = r0 - 1 + r;
            f32x4 val = {0, 0, 0, 0};
            if ((unsigned)gr < (unsigned)HH)
                val = *(const f32x4*)(xb + (c * HH + gr) * WW + q * 4);
            *(f32x4*)&s_x[(c * LDSROWS + r) * LROW + q * 4] = val;
        }
    }

    // channel words: uniform -> s_load once, SALU thereafter
    const unsigned* cwp = ws_cw + oc * 8;
    const unsigned cw0 = cwp[0], cw1 = cwp[1], cw2 = cwp[2], cw3 = cwp[3];
    const unsigned cw4 = cwp[4], cw5 = cwp[5], cw6 = cwp[6], cw7 = cwp[7];

    // opaque VGPR zero -> weight pointer rides the VECTOR path (vmcnt, in-order)
    unsigned zoff;
    asm volatile("v_mov_b32 %0, 0" : "=v"(zoff));
    const char* wbase = (const char*)(ws_w + (size_t)oc * SET_LEN * 12) + zoff;

    __syncthreads();

    // ---- fused conv + bias + running max; 2 rows per lane, packed fp32 ----
    const bool  lanev = (tx < WW);
    const int   txr   = lanev ? tx : 0;            // clamp for safe LDS reads
    const int   txl   = (txr > 0)  ? txr - 1 : 0;  // in-row clamp; masked by lm
    const int   txp   = (txr < 55) ? txr + 1 : 55; // in-row clamp; masked by rm
    const float lm    = (txr == 0)  ? 0.0f : 1.0f; // left-edge tap mask
    const float rm    = (txr == 55) ? 0.0f : 1.0f; // right-edge tap mask

    f32x2 acc = { -__builtin_inff(), -__builtin_inff() };
    int ccur = -1;
    f32x2 v00={0,0},v01={0,0},v02={0,0};
    f32x2 v10={0,0},v11={0,0},v12={0,0};
    f32x2 v20={0,0},v21={0,0},v22={0,0};

#define NBLOAD(C_) do {                                                        \
        const float* sp = &s_x[((C_) * LDSROWS + grp * 2) * LROW];             \
        const float n00=sp[txl]*lm,        n01=sp[txr],        n02=sp[txp]*rm; \
        const float n10=sp[LROW+txl]*lm,   n11=sp[LROW+txr],   n12=sp[LROW+txp]*rm; \
        const float n20=sp[2*LROW+txl]*lm, n21=sp[2*LROW+txr], n22=sp[2*LROW+txp]*rm; \
        const float n30=sp[3*LROW+txl]*lm, n31=sp[3*LROW+txr], n32=sp[3*LROW+txp]*rm; \
        v00=(f32x2){n00,n10}; v01=(f32x2){n01,n11}; v02=(f32x2){n02,n12};      \
        v10=(f32x2){n10,n20}; v11=(f32x2){n11,n21}; v12=(f32x2){n12,n22};      \
        v20=(f32x2){n20,n30}; v21=(f32x2){n21,n31}; v22=(f32x2){n22,n32};      \
    } while (0)

#define ENT(K, CW, J) do {                                                     \
        const int c_ = (int)(((CW) >> (4 * (J))) & 15u);                       \
        if (c_ != ccur) { ccur = c_; NBLOAD(c_); }                             \
        const char* wp_ = wbase + (K) * 48;                                    \
        const ulonglong2 A  = *(const ulonglong2*)(wp_);                       \
        const ulonglong2 Bq = *(const ulonglong2*)(wp_ + 16);                  \
        const ulonglong2 Cq = *(const ulonglong2*)(wp_ + 32);                  \
        f32x2 t0 = pk_mul_vlo(A.x,  v00);                                      \
        t0       = pk_fma_vhi(A.x,  v01, t0);                                  \
        t0       = pk_fma_vlo(A.y,  v02, t0);                                  \
        f32x2 t1 = pk_mul_vhi(A.y,  v10);                                      \
        t1       = pk_fma_vlo(Bq.x, v11, t1);                                  \
        t1       = pk_fma_vhi(Bq.x, v12, t1);                                  \
        f32x2 t2 = pk_mul_vlo(Bq.y, v20);                                      \
        t2       = pk_fma_vhi(Bq.y, v21, t2);                                  \
        t2       = pk_fma_vlo(Cq.x, v22, t2);                                  \
        f32x2 s_ = pk_add_vv(t0, t1);                                          \
        s_       = pk_add_vv(s_, t2);                                          \
        s_       = pk_add_vhi(Cq.x, s_);                                       \
        acc.x = fmaxf(acc.x, s_.x);                                            \
        acc.y = fmaxf(acc.y, s_.y);                                            \
    } while (0)

#define GRP8(G, CW)                                                            \
    ENT((G)*8+0, CW, 0); ENT((G)*8+1, CW, 1); ENT((G)*8+2, CW, 2);             \
    ENT((G)*8+3, CW, 3); ENT((G)*8+4, CW, 4); ENT((G)*8+5, CW, 5);             \
    ENT((G)*8+6, CW, 6); ENT((G)*8+7, CW, 7);

    GRP8(0, cw0) GRP8(1, cw1) GRP8(2, cw2) GRP8(3, cw3)
    GRP8(4, cw4) GRP8(5, cw5) GRP8(6, cw6) GRP8(7, cw7)

#undef GRP8
#undef ENT
#undef NBLOAD

    if (lanev) {
        const size_t o = (((size_t)b * OUT_CH + oc) * HH + (r0 + grp * 2)) * WW + tx;
        out[o]      = acc.x;   // row grp*2
        out[o + WW] = acc.y;   // row grp*2 + 1
    }
}

// ---------------- fallback (R13-style): in-block sort + LDS weight table ----------------
__global__ __launch_bounds__(256, 2)
void rptn_fused_fallback(const float* __restrict__ x,
                         const float* __restrict__ w,
                         const float* __restrict__ bias,
                         const int*   __restrict__ idx,
                         float*       __restrict__ out) {
    const int oc   = blockIdx.x;
    const int tile = blockIdx.y;
    const int b    = blockIdx.z;
    const int tid  = threadIdx.x;
    const int tx   = tid & 63;
    const int grp  = __builtin_amdgcn_readfirstlane(tid >> 6);

    __shared__ float s_x[LDS_XN];
    __shared__ f32x4 s_w[SET_LEN * 3];
    __shared__ int   s_cnt[IN_CH];
    __shared__ int   s_pos[IN_CH];
    __shared__ int   s_eord[SET_LEN];

    if (tid < IN_CH) s_cnt[tid] = 0;
    __syncthreads();
    int my_e = 0;
    if (tid < SET_LEN) {
        my_e = idx[oc * SET_LEN + tid];
        atomicAdd(&s_cnt[my_e >> 8], 1);
    }
    __syncthreads();
    if (tid == 0) {
        int run = 0;
        for (int c = 0; c < IN_CH; ++c) { s_pos[c] = run; run += s_cnt[c]; }
    }
    __syncthreads();
    if (tid < SET_LEN) {
        int p = atomicAdd(&s_pos[my_e >> 8], 1);
        s_eord[p] = my_e;
    }
    __syncthreads();

    float* s_wf = (float*)s_w;
    for (int i = tid; i < SET_LEN * 12; i += 256) {
        const int j    = i / 12;
        const int comp = i - j * 12;
        const int e    = s_eord[j];
        float v;
        if (comp < 9)        v = w[e * 9 + comp];
        else if (comp == 9)  v = bias[e];
        else if (comp == 10) v = __int_as_float(e >> 8);
        else                 v = 0.0f;
        s_wf[j * 12 + comp] = v;
    }

    const int r0 = tile * TILEROWS;
    const float* xb = x + (size_t)b * IN_CH * HH * WW;
    #pragma unroll
    for (int it = 0; it < 9; ++it) {
        const int v = tid + it * 256;
        if (it < 8 || v < NVEC) {
            const int c   = v / (LDSROWS * 14);
            const int rem = v - c * (LDSROWS * 14);
            const int r   = rem / 14;
            const int q   = rem - r * 14;
            const int gr  = r0 - 1 + r;
            f32x4 val = {0, 0, 0, 0};
            if ((unsigned)gr < (unsigned)HH)
                val = *(const f32x4*)(xb + (c * HH + gr) * WW + q * 4);
            *(f32x4*)&s_x[(c * LDSROWS + r) * LROW + q * 4] = val;
        }
    }
    __syncthreads();

    const bool  lanev = (tx < WW);
    const int   txr   = lanev ? tx : 0;
    const int   txl   = (txr > 0)  ? txr - 1 : 0;
    const int   txp   = (txr < 55) ? txr + 1 : 55;
    const float lm    = (txr == 0)  ? 0.0f : 1.0f;
    const float rm    = (txr == 55) ? 0.0f : 1.0f;

    f32x2 acc = { -__builtin_inff(), -__builtin_inff() };
    int ccur = -1;
    f32x2 v00={0,0},v01={0,0},v02={0,0};
    f32x2 v10={0,0},v11={0,0},v12={0,0};
    f32x2 v20={0,0},v21={0,0},v22={0,0};

    #pragma unroll 2
    for (int k = 0; k < SET_LEN; ++k) {
        const f32x4 q0 = s_w[k * 3 + 0];
        const f32x4 q1 = s_w[k * 3 + 1];
        const f32x4 q2 = s_w[k * 3 + 2];
        const int c = __float_as_int(q2.z);
        if (c != ccur) {
            ccur = c;
            const float* sp = &s_x[(c * LDSROWS + grp * 2) * LROW];
            const float n00=sp[txl]*lm,        n01=sp[txr],        n02=sp[txp]*rm;
            const float n10=sp[LROW+txl]*lm,   n11=sp[LROW+txr],   n12=sp[LROW+txp]*rm;
            const float n20=sp[2*LROW+txl]*lm, n21=sp[2*LROW+txr], n22=sp[2*LROW+txp]*rm;
            const float n30=sp[3*LROW+txl]*lm, n31=sp[3*LROW+txr], n32=sp[3*LROW+txp]*rm;
            v00=(f32x2){n00,n10}; v01=(f32x2){n01,n11}; v02=(f32x2){n02,n12};
            v10=(f32x2){n10,n20}; v11=(f32x2){n11,n21}; v12=(f32x2){n12,n22};
            v20=(f32x2){n20,n30}; v21=(f32x2){n21,n31}; v22=(f32x2){n22,n32};
        }
        f32x2 t0 = __builtin_elementwise_fma(splat2(q0.z), v02,
                   __builtin_elementwise_fma(splat2(q0.y), v01,
                   __builtin_elementwise_fma(splat2(q0.x), v00, splat2(q2.y))));
        f32x2 t1 = __builtin_elementwise_fma(splat2(q1.y), v12,
                   __builtin_elementwise_fma(splat2(q1.x), v11,
                                             splat2(q0.w) * v10));
        f32x2 t2 = __builtin_elementwise_fma(splat2(q2.x), v22,
                   __builtin_elementwise_fma(splat2(q1.w), v21,
                                             splat2(q1.z) * v20));
        const f32x2 s = t0 + (t1 + t2);
        acc.x = fmaxf(acc.x, s.x);
        acc.y = fmaxf(acc.y, s.y);
    }

    if (lanev) {
        const size_t o = (((size_t)b * OUT_CH + oc) * HH + (r0 + grp * 2)) * WW + tx;
        out[o]      = acc.x;
        out[o + WW] = acc.y;
    }
}

extern "C" void kernel_launch(void* const* d_in, const int* in_sizes, int n_in,
                              void* d_out, int out_size, void* d_ws, size_t ws_size,
                              hipStream_t stream) {
    const float* x    = (const float*)d_in[0];
    const float* w    = (const float*)d_in[1];
    const float* bias = (const float*)d_in[2];
    const int*   idx  = (const int*)d_in[3];
    float*       out  = (float*)d_out;

    dim3 grid(OUT_CH, NTILES, BB);   // oc fastest -> x tile L2 reuse
    dim3 block(256);

    if (ws_size >= (size_t)WS_NEEDED) {
        unsigned* ws_cw = (unsigned*)((char*)d_ws + WS_CW_OFF);
        float*    ws_w  = (float*)((char*)d_ws + WS_W_OFF);
        rptn_presort<<<dim3(OUT_CH), dim3(64), 0, stream>>>(w, bias, idx, ws_cw, ws_w);
        rptn_fused_kernel<<<grid, block, 0, stream>>>(x, ws_cw, ws_w, out);
    } else {
        rptn_fused_fallback<<<grid, block, 0, stream>>>(x, w, bias, idx, out);
    }
}

// Round 15
// 141.473 us; speedup vs baseline: 1.1763x; 1.1763x over previous
//
#include <hip/hip_runtime.h>

#define IN_CH    16
#define OUT_CH   64
#define SET_LEN  64
#define BB       8
#define HH       56
#define WW       56

#define TILEROWS 8              // output rows per block (56 = 7*8)
#define NTILES   7
#define LDSROWS  (TILEROWS + 2) // staged rows incl. halo
#define LROW     56             // exactly the data columns; 224B row stride
#define LDS_XN   (IN_CH * LDSROWS * LROW)   // 8960 floats = 35840 B
#define NVEC     (IN_CH * LDSROWS * 14)     // 2240 float4 transfers

#define WS_NEEDED (OUT_CH * SET_LEN * 12 * 4)   // 196608 B

typedef float f32x2 __attribute__((ext_vector_type(2)));
typedef float f32x4 __attribute__((ext_vector_type(4)));

static __device__ __forceinline__ f32x2 splat2(float s) { return (f32x2){s, s}; }

// ---- packed-fp32 VOP3P helpers: SGPR-pair half broadcast to both lanes ----
static __device__ __forceinline__ f32x2 pk_mul_slo(unsigned long long sp, f32x2 b) {
    f32x2 d;
    asm("v_pk_mul_f32 %0, %1, %2 op_sel:[0,0] op_sel_hi:[0,1]"
        : "=v"(d) : "s"(sp), "v"(b));
    return d;
}
static __device__ __forceinline__ f32x2 pk_mul_shi(unsigned long long sp, f32x2 b) {
    f32x2 d;
    asm("v_pk_mul_f32 %0, %1, %2 op_sel:[1,0] op_sel_hi:[1,1]"
        : "=v"(d) : "s"(sp), "v"(b));
    return d;
}
static __device__ __forceinline__ f32x2 pk_fma_slo(unsigned long long sp, f32x2 b, f32x2 c) {
    f32x2 d;
    asm("v_pk_fma_f32 %0, %1, %2, %3 op_sel:[0,0,0] op_sel_hi:[0,1,1]"
        : "=v"(d) : "s"(sp), "v"(b), "v"(c));
    return d;
}
static __device__ __forceinline__ f32x2 pk_fma_shi(unsigned long long sp, f32x2 b, f32x2 c) {
    f32x2 d;
    asm("v_pk_fma_f32 %0, %1, %2, %3 op_sel:[1,0,0] op_sel_hi:[1,1,1]"
        : "=v"(d) : "s"(sp), "v"(b), "v"(c));
    return d;
}
static __device__ __forceinline__ f32x2 pk_add_vv(f32x2 a, f32x2 b) {
    f32x2 d;
    asm("v_pk_add_f32 %0, %1, %2 op_sel:[0,0] op_sel_hi:[1,1]"
        : "=v"(d) : "v"(a), "v"(b));
    return d;
}
static __device__ __forceinline__ f32x2 pk_add_shi(unsigned long long sp, f32x2 b) {
    f32x2 d;
    asm("v_pk_add_f32 %0, %1, %2 op_sel:[1,0] op_sel_hi:[1,1]"
        : "=v"(d) : "s"(sp), "v"(b));
    return d;
}

// ---------------- pre-kernel: per-oc counting sort + weight gather ----------------
// record per entry (12 floats, 48B): w0..w8, bias, chan(bits), pad
__global__ __launch_bounds__(64)
void rptn_presort(const float* __restrict__ w, const float* __restrict__ bias,
                  const int* __restrict__ idx, float* __restrict__ ws_w) {
    const int oc = blockIdx.x;
    const int t  = threadIdx.x;
    __shared__ int cnt[IN_CH], pos[IN_CH], eord[SET_LEN];

    if (t < IN_CH) cnt[t] = 0;
    __syncthreads();
    const int e = idx[oc * SET_LEN + t];
    const int c = e >> 8;
    atomicAdd(&cnt[c], 1);
    __syncthreads();
    if (t == 0) {
        int run = 0;
        for (int i = 0; i < IN_CH; ++i) { pos[i] = run; run += cnt[i]; }
    }
    __syncthreads();
    const int p = atomicAdd(&pos[c], 1);
    eord[p] = e;
    __syncthreads();

    const int    es  = eord[t];
    float*       dst = ws_w + ((size_t)oc * SET_LEN + t) * 12;
    const float* src = w + es * 9;
    #pragma unroll
    for (int i = 0; i < 9; ++i) dst[i] = src[i];
    dst[9]  = bias[es];
    dst[10] = __int_as_float(es >> 8);
    dst[11] = 0.0f;
}

// ---------------- main fused kernel: 4 px/lane, SMEM weights, pk math ----------------
__global__ __launch_bounds__(128, 2)
void rptn_fused_kernel(const float* __restrict__ x,
                       const float* __restrict__ ws_w,
                       float*       __restrict__ out) {
    const int oc   = blockIdx.x;   // fastest-varying -> x tile reused across oc in L2
    const int tile = blockIdx.y;
    const int b    = blockIdx.z;
    const int tid  = threadIdx.x;
    const int tx   = tid & 63;
    const int grp  = __builtin_amdgcn_readfirstlane(tid >> 6); // wave id: 0/1

    __shared__ float s_x[LDS_XN];

    // ---- stage x tile: aligned vec4 loads + vec4 LDS writes (128 threads) ----
    const int r0 = tile * TILEROWS;
    const float* xb = x + (size_t)b * IN_CH * HH * WW;
    #pragma unroll
    for (int it = 0; it < 18; ++it) {              // 17 full + 64-tail (2240 = 17*128+64)
        const int v = tid + it * 128;
        if (it < 17 || tid < 64) {
            const int c   = v / (LDSROWS * 14);
            const int rem = v - c * (LDSROWS * 14);
            const int r   = rem / 14;
            const int q   = rem - r * 14;
            const int gr  = r0 - 1 + r;
            f32x4 val = {0, 0, 0, 0};
            if ((unsigned)gr < (unsigned)HH)
                val = *(const f32x4*)(xb + (c * HH + gr) * WW + q * 4);
            *(f32x4*)&s_x[(c * LDSROWS + r) * LROW + q * 4] = val;
        }
    }
    __syncthreads();

    // ---- fused conv + bias + running max; 4 rows per lane (2 pk pairs) ----
    const bool  lanev = (tx < WW);
    const int   txr   = lanev ? tx : 0;            // clamp for safe LDS reads
    const int   txl   = (txr > 0)  ? txr - 1 : 0;  // masked by lm
    const int   txp   = (txr < 55) ? txr + 1 : 55; // masked by rm
    const float lm    = (txr == 0)  ? 0.0f : 1.0f;
    const float rm    = (txr == 55) ? 0.0f : 1.0f;

    f32x2 accA = { -__builtin_inff(), -__builtin_inff() };  // rows grp*4 + 0,1
    f32x2 accB = { -__builtin_inff(), -__builtin_inff() };  // rows grp*4 + 2,3
    int ccur = -1;
    // 5 vertical tap pairs x 3 cols: P[t] = {n[t], n[t+1]}, rows n0..n5
    f32x2 P0l={0,0},P0c={0,0},P0r={0,0};
    f32x2 P1l={0,0},P1c={0,0},P1r={0,0};
    f32x2 P2l={0,0},P2c={0,0},P2r={0,0};
    f32x2 P3l={0,0},P3c={0,0},P3r={0,0};
    f32x2 P4l={0,0},P4c={0,0},P4r={0,0};

    const ulonglong2* wt = (const ulonglong2*)ws_w + (size_t)oc * SET_LEN * 3;

    #pragma unroll 8
    for (int k = 0; k < SET_LEN; ++k) {
        const ulonglong2 A  = wt[k * 3 + 0];   // {w0w1, w2w3}   (s_load_dwordx4)
        const ulonglong2 Bq = wt[k * 3 + 1];   // {w4w5, w6w7}
        const ulonglong2 Cq = wt[k * 3 + 2];   // {w8·bias, chan·pad}
        const int c = (int)(unsigned int)(Cq.y & 0xffffffffULL);
        if (c != ccur) {                       // wave-uniform branch (~16 of 64 iters)
            ccur = c;
            const float* sp = &s_x[(c * LDSROWS + grp * 4) * LROW];
            float nl[6], nc[6], nr[6];
            #pragma unroll
            for (int t = 0; t < 6; ++t) {
                nl[t] = sp[t * LROW + txl] * lm;
                nc[t] = sp[t * LROW + txr];
                nr[t] = sp[t * LROW + txp] * rm;
            }
            P0l=(f32x2){nl[0],nl[1]}; P0c=(f32x2){nc[0],nc[1]}; P0r=(f32x2){nr[0],nr[1]};
            P1l=(f32x2){nl[1],nl[2]}; P1c=(f32x2){nc[1],nc[2]}; P1r=(f32x2){nr[1],nr[2]};
            P2l=(f32x2){nl[2],nl[3]}; P2c=(f32x2){nc[2],nc[3]}; P2r=(f32x2){nr[2],nr[3]};
            P3l=(f32x2){nl[3],nl[4]}; P3c=(f32x2){nc[3],nc[4]}; P3r=(f32x2){nr[3],nr[4]};
            P4l=(f32x2){nl[4],nl[5]}; P4c=(f32x2){nc[4],nc[5]}; P4r=(f32x2){nr[4],nr[5]};
        }
        // pair A (rows +0,+1): taps P0,P1,P2
        f32x2 t0 = pk_mul_slo(A.x,  P0l);
        t0       = pk_fma_shi(A.x,  P0c, t0);
        t0       = pk_fma_slo(A.y,  P0r, t0);
        f32x2 t1 = pk_mul_shi(A.y,  P1l);
        t1       = pk_fma_slo(Bq.x, P1c, t1);
        t1       = pk_fma_shi(Bq.x, P1r, t1);
        f32x2 t2 = pk_mul_slo(Bq.y, P2l);
        t2       = pk_fma_shi(Bq.y, P2c, t2);
        t2       = pk_fma_slo(Cq.x, P2r, t2);
        f32x2 sA = pk_add_vv(t0, t1);
        sA       = pk_add_vv(sA, t2);
        sA       = pk_add_shi(Cq.x, sA);       // + bias
        accA.x = fmaxf(accA.x, sA.x);
        accA.y = fmaxf(accA.y, sA.y);
        // pair B (rows +2,+3): taps P2,P3,P4
        f32x2 u0 = pk_mul_slo(A.x,  P2l);
        u0       = pk_fma_shi(A.x,  P2c, u0);
        u0       = pk_fma_slo(A.y,  P2r, u0);
        f32x2 u1 = pk_mul_shi(A.y,  P3l);
        u1       = pk_fma_slo(Bq.x, P3c, u1);
        u1       = pk_fma_shi(Bq.x, P3r, u1);
        f32x2 u2 = pk_mul_slo(Bq.y, P4l);
        u2       = pk_fma_shi(Bq.y, P4c, u2);
        u2       = pk_fma_slo(Cq.x, P4r, u2);
        f32x2 sB = pk_add_vv(u0, u1);
        sB       = pk_add_vv(sB, u2);
        sB       = pk_add_shi(Cq.x, sB);
        accB.x = fmaxf(accB.x, sB.x);
        accB.y = fmaxf(accB.y, sB.y);
    }

    if (lanev) {
        const size_t o = (((size_t)b * OUT_CH + oc) * HH + (r0 + grp * 4)) * WW + tx;
        out[o]          = accA.x;
        out[o + WW]     = accA.y;
        out[o + 2 * WW] = accB.x;
        out[o + 3 * WW] = accB.y;
    }
}

// ---------------- fallback (R13-style, 2 px/lane, no workspace) ----------------
__global__ __launch_bounds__(256, 2)
void rptn_fused_fallback(const float* __restrict__ x,
                         const float* __restrict__ w,
                         const float* __restrict__ bias,
                         const int*   __restrict__ idx,
                         float*       __restrict__ out) {
    const int oc   = blockIdx.x;
    const int tile = blockIdx.y;
    const int b    = blockIdx.z;
    const int tid  = threadIdx.x;
    const int tx   = tid & 63;
    const int grp  = __builtin_amdgcn_readfirstlane(tid >> 6);

    __shared__ float s_x[LDS_XN];
    __shared__ f32x4 s_w[SET_LEN * 3];
    __shared__ int   s_cnt[IN_CH];
    __shared__ int   s_pos[IN_CH];
    __shared__ int   s_eord[SET_LEN];

    if (tid < IN_CH) s_cnt[tid] = 0;
    __syncthreads();
    int my_e = 0;
    if (tid < SET_LEN) {
        my_e = idx[oc * SET_LEN + tid];
        atomicAdd(&s_cnt[my_e >> 8], 1);
    }
    __syncthreads();
    if (tid == 0) {
        int run = 0;
        for (int c = 0; c < IN_CH; ++c) { s_pos[c] = run; run += s_cnt[c]; }
    }
    __syncthreads();
    if (tid < SET_LEN) {
        int p = atomicAdd(&s_pos[my_e >> 8], 1);
        s_eord[p] = my_e;
    }
    __syncthreads();

    float* s_wf = (float*)s_w;
    for (int i = tid; i < SET_LEN * 12; i += 256) {
        const int j    = i / 12;
        const int comp = i - j * 12;
        const int e    = s_eord[j];
        float v;
        if (comp < 9)        v = w[e * 9 + comp];
        else if (comp == 9)  v = bias[e];
        else if (comp == 10) v = __int_as_float(e >> 8);
        else                 v = 0.0f;
        s_wf[j * 12 + comp] = v;
    }

    const int r0 = tile * TILEROWS;
    const float* xb = x + (size_t)b * IN_CH * HH * WW;
    #pragma unroll
    for (int it = 0; it < 9; ++it) {
        const int v = tid + it * 256;
        if (it < 8 || v < NVEC) {
            const int c   = v / (LDSROWS * 14);
            const int rem = v - c * (LDSROWS * 14);
            const int r   = rem / 14;
            const int q   = rem - r * 14;
            const int gr  = r0 - 1 + r;
            f32x4 val = {0, 0, 0, 0};
            if ((unsigned)gr < (unsigned)HH)
                val = *(const f32x4*)(xb + (c * HH + gr) * WW + q * 4);
            *(f32x4*)&s_x[(c * LDSROWS + r) * LROW + q * 4] = val;
        }
    }
    __syncthreads();

    const bool  lanev = (tx < WW);
    const int   txr   = lanev ? tx : 0;
    const int   txl   = (txr > 0)  ? txr - 1 : 0;
    const int   txp   = (txr < 55) ? txr + 1 : 55;
    const float lm    = (txr == 0)  ? 0.0f : 1.0f;
    const float rm    = (txr == 55) ? 0.0f : 1.0f;

    f32x2 acc = { -__builtin_inff(), -__builtin_inff() };
    int ccur = -1;
    f32x2 v00={0,0},v01={0,0},v02={0,0};
    f32x2 v10={0,0},v11={0,0},v12={0,0};
    f32x2 v20={0,0},v21={0,0},v22={0,0};

    #pragma unroll 2
    for (int k = 0; k < SET_LEN; ++k) {
        const f32x4 q0 = s_w[k * 3 + 0];
        const f32x4 q1 = s_w[k * 3 + 1];
        const f32x4 q2 = s_w[k * 3 + 2];
        const int c = __float_as_int(q2.z);
        if (c != ccur) {
            ccur = c;
            const float* sp = &s_x[(c * LDSROWS + grp * 2) * LROW];
            const float n00=sp[txl]*lm,        n01=sp[txr],        n02=sp[txp]*rm;
            const float n10=sp[LROW+txl]*lm,   n11=sp[LROW+txr],   n12=sp[LROW+txp]*rm;
            const float n20=sp[2*LROW+txl]*lm, n21=sp[2*LROW+txr], n22=sp[2*LROW+txp]*rm;
            const float n30=sp[3*LROW+txl]*lm, n31=sp[3*LROW+txr], n32=sp[3*LROW+txp]*rm;
            v00=(f32x2){n00,n10}; v01=(f32x2){n01,n11}; v02=(f32x2){n02,n12};
            v10=(f32x2){n10,n20}; v11=(f32x2){n11,n21}; v12=(f32x2){n12,n22};
            v20=(f32x2){n20,n30}; v21=(f32x2){n21,n31}; v22=(f32x2){n22,n32};
        }
        f32x2 t0 = __builtin_elementwise_fma(splat2(q0.z), v02,
                   __builtin_elementwise_fma(splat2(q0.y), v01,
                   __builtin_elementwise_fma(splat2(q0.x), v00, splat2(q2.y))));
        f32x2 t1 = __builtin_elementwise_fma(splat2(q1.y), v12,
                   __builtin_elementwise_fma(splat2(q1.x), v11,
                                             splat2(q0.w) * v10));
        f32x2 t2 = __builtin_elementwise_fma(splat2(q2.x), v22,
                   __builtin_elementwise_fma(splat2(q1.w), v21,
                                             splat2(q1.z) * v20));
        const f32x2 s = t0 + (t1 + t2);
        acc.x = fmaxf(acc.x, s.x);
        acc.y = fmaxf(acc.y, s.y);
    }

    if (lanev) {
        const size_t o = (((size_t)b * OUT_CH + oc) * HH + (r0 + grp * 2)) * WW + tx;
        out[o]      = acc.x;
        out[o + WW] = acc.y;
    }
}

extern "C" void kernel_launch(void* const* d_in, const int* in_sizes, int n_in,
                              void* d_out, int out_size, void* d_ws, size_t ws_size,
                              hipStream_t stream) {
    const float* x    = (const float*)d_in[0];
    const float* w    = (const float*)d_in[1];
    const float* bias = (const float*)d_in[2];
    const int*   idx  = (const int*)d_in[3];
    float*       out  = (float*)d_out;

    dim3 grid(OUT_CH, NTILES, BB);   // oc fastest -> x tile L2 reuse

    if (ws_size >= (size_t)WS_NEEDED) {
        float* ws_w = (float*)d_ws;
        rptn_presort<<<dim3(OUT_CH), dim3(64), 0, stream>>>(w, bias, idx, ws_w);
        rptn_fused_kernel<<<grid, dim3(128), 0, stream>>>(x, ws_w, out);
    } else {
        rptn_fused_fallback<<<grid, dim3(256), 0, stream>>>(x, w, bias, idx, out);
    }
}

// Round 16
// 138.359 us; speedup vs baseline: 1.2028x; 1.0225x over previous
//
#include <hip/hip_runtime.h>

#define IN_CH    16
#define OUT_CH   64
#define SET_LEN  64
#define BB       8
#define HH       56
#define WW       56

#define TILEROWS 8              // output rows per block (56 = 7*8)
#define NTILES   7

// ws layout: [0,2048): packed channel words (8 u32/oc); [2048,+192K): weight records
#define WS_CW_OFF 0
#define WS_W_OFF  2048
#define WS_NEEDED (WS_W_OFF + OUT_CH * SET_LEN * 12 * 4)   // 198656 B

typedef float f32x2 __attribute__((ext_vector_type(2)));
typedef float f32x4 __attribute__((ext_vector_type(4)));

static __device__ __forceinline__ f32x2 splat2(float s) { return (f32x2){s, s}; }

// ---- packed-fp32 VOP3P helpers: SGPR-pair half broadcast to both lanes ----
static __device__ __forceinline__ f32x2 pk_mul_slo(unsigned long long sp, f32x2 b) {
    f32x2 d;
    asm("v_pk_mul_f32 %0, %1, %2 op_sel:[0,0] op_sel_hi:[0,1]"
        : "=v"(d) : "s"(sp), "v"(b));
    return d;
}
static __device__ __forceinline__ f32x2 pk_mul_shi(unsigned long long sp, f32x2 b) {
    f32x2 d;
    asm("v_pk_mul_f32 %0, %1, %2 op_sel:[1,0] op_sel_hi:[1,1]"
        : "=v"(d) : "s"(sp), "v"(b));
    return d;
}
static __device__ __forceinline__ f32x2 pk_fma_slo(unsigned long long sp, f32x2 b, f32x2 c) {
    f32x2 d;
    asm("v_pk_fma_f32 %0, %1, %2, %3 op_sel:[0,0,0] op_sel_hi:[0,1,1]"
        : "=v"(d) : "s"(sp), "v"(b), "v"(c));
    return d;
}
static __device__ __forceinline__ f32x2 pk_fma_shi(unsigned long long sp, f32x2 b, f32x2 c) {
    f32x2 d;
    asm("v_pk_fma_f32 %0, %1, %2, %3 op_sel:[1,0,0] op_sel_hi:[1,1,1]"
        : "=v"(d) : "s"(sp), "v"(b), "v"(c));
    return d;
}
static __device__ __forceinline__ f32x2 pk_add_vv(f32x2 a, f32x2 b) {
    f32x2 d;
    asm("v_pk_add_f32 %0, %1, %2 op_sel:[0,0] op_sel_hi:[1,1]"
        : "=v"(d) : "v"(a), "v"(b));
    return d;
}
static __device__ __forceinline__ f32x2 pk_add_shi(unsigned long long sp, f32x2 b) {
    f32x2 d;
    asm("v_pk_add_f32 %0, %1, %2 op_sel:[1,0] op_sel_hi:[1,1]"
        : "=v"(d) : "s"(sp), "v"(b));
    return d;
}

// ---------------- pre-kernel: per-oc counting sort + weight gather + chan words ----
// record per entry (12 floats, 48B): w0..w8, bias, chan(bits), pad
__global__ __launch_bounds__(64)
void rptn_presort(const float* __restrict__ w, const float* __restrict__ bias,
                  const int* __restrict__ idx, unsigned* __restrict__ ws_cw,
                  float* __restrict__ ws_w) {
    const int oc = blockIdx.x;
    const int t  = threadIdx.x;
    __shared__ int cnt[IN_CH], pos[IN_CH], eord[SET_LEN];

    if (t < IN_CH) cnt[t] = 0;
    __syncthreads();
    const int e = idx[oc * SET_LEN + t];
    const int c = e >> 8;
    atomicAdd(&cnt[c], 1);
    __syncthreads();
    if (t == 0) {
        int run = 0;
        for (int i = 0; i < IN_CH; ++i) { pos[i] = run; run += cnt[i]; }
    }
    __syncthreads();
    const int p = atomicAdd(&pos[c], 1);
    eord[p] = e;
    __syncthreads();

    const int    es  = eord[t];
    float*       dst = ws_w + ((size_t)oc * SET_LEN + t) * 12;
    const float* src = w + es * 9;
    #pragma unroll
    for (int i = 0; i < 9; ++i) dst[i] = src[i];
    dst[9]  = bias[es];
    dst[10] = __int_as_float(es >> 8);
    dst[11] = 0.0f;

    if (t < 8) {                     // pack 8 sorted channel ids per u32
        unsigned wd = 0;
        #pragma unroll
        for (int j = 0; j < 8; ++j)
            wd |= ((unsigned)(eord[t * 8 + j] >> 8)) << (4 * j);
        ws_cw[oc * 8 + t] = wd;
    }
}

// ------- main fused kernel: NO LDS, L2-direct neighborhood, SMEM weights, pk math -------
__global__ __launch_bounds__(256, 4)
void rptn_fused_kernel(const float* __restrict__ x,
                       const unsigned* __restrict__ ws_cw,
                       const float* __restrict__ ws_w,
                       float*       __restrict__ out) {
    const int oc   = blockIdx.x;   // fastest-varying -> x rows reused across oc in L2
    const int tile = blockIdx.y;
    const int b    = blockIdx.z;
    const int tid  = threadIdx.x;
    const int tx   = tid & 63;
    const int grp  = __builtin_amdgcn_readfirstlane(tid >> 6); // wave id 0..3

    const int r0 = tile * TILEROWS;
    const float* xb = x + (size_t)b * IN_CH * HH * WW;

    // per-lane horizontal taps + masks
    const bool  lanev = (tx < WW);
    const int   txr   = lanev ? tx : 0;
    const int   txl   = (txr > 0)  ? txr - 1 : 0;
    const int   txp   = (txr < 55) ? txr + 1 : 55;
    const float lm    = (txr == 0)  ? 0.0f : 1.0f;
    const float rm    = (txr == 55) ? 0.0f : 1.0f;

    // vertical rows needed: r0 + grp*2 - 1 + t, t=0..3 (wave-uniform masks)
    int   vr[4];
    float vm[4];
    #pragma unroll
    for (int t = 0; t < 4; ++t) {
        const int rr = r0 + grp * 2 - 1 + t;
        vm[t] = ((unsigned)rr < (unsigned)HH) ? 1.0f : 0.0f;
        vr[t] = rr < 0 ? 0 : (rr > HH - 1 ? HH - 1 : rr);
    }

    // channel words: uniform s_load once -> pure SALU thereafter
    const unsigned* cwp = ws_cw + oc * 8;
    const unsigned cw0 = cwp[0], cw1 = cwp[1], cw2 = cwp[2], cw3 = cwp[3];
    const unsigned cw4 = cwp[4], cw5 = cwp[5], cw6 = cwp[6], cw7 = cwp[7];

    // weight records: uniform -> s_load_dwordx4 with immediate offsets (affine in k)
    const ulonglong2* wt = (const ulonglong2*)ws_w + (size_t)oc * SET_LEN * 3;

    f32x2 acc = { -__builtin_inff(), -__builtin_inff() };
    int ccur = -1;
    f32x2 v00={0,0},v01={0,0},v02={0,0};
    f32x2 v10={0,0},v11={0,0},v12={0,0};
    f32x2 v20={0,0},v21={0,0},v22={0,0};

#define NBLOAD(C_) do {                                                        \
        const float* cb = xb + (C_) * (HH * WW);                               \
        float nl[4], nc[4], nr[4];                                             \
        _Pragma("unroll")                                                      \
        for (int t = 0; t < 4; ++t) {      /* 12 coalesced L2 loads (vmcnt) */ \
            const float* rp = cb + vr[t] * WW;                                 \
            nl[t] = rp[txl]; nc[t] = rp[txr]; nr[t] = rp[txp];                 \
        }                                                                      \
        _Pragma("unroll")                                                      \
        for (int t = 0; t < 4; ++t) {      /* masks applied after loads */     \
            nl[t] *= lm * vm[t]; nc[t] *= vm[t]; nr[t] *= rm * vm[t];          \
        }                                                                      \
        v00=(f32x2){nl[0],nl[1]}; v01=(f32x2){nc[0],nc[1]}; v02=(f32x2){nr[0],nr[1]}; \
        v10=(f32x2){nl[1],nl[2]}; v11=(f32x2){nc[1],nc[2]}; v12=(f32x2){nr[1],nr[2]}; \
        v20=(f32x2){nl[2],nl[3]}; v21=(f32x2){nc[2],nc[3]}; v22=(f32x2){nr[2],nr[3]}; \
    } while (0)

#define ENT(K, CW, J) do {                                                     \
        const int c_ = (int)(((CW) >> (4 * (J))) & 15u);                       \
        if (c_ != ccur) { ccur = c_; NBLOAD(c_); }                             \
        const ulonglong2 A  = wt[(K) * 3 + 0];  /* {w0w1, w2w3} */             \
        const ulonglong2 Bq = wt[(K) * 3 + 1];  /* {w4w5, w6w7} */             \
        const ulonglong2 Cq = wt[(K) * 3 + 2];  /* {w8·bias, chan·pad} */      \
        f32x2 t0 = pk_mul_slo(A.x,  v00);                                      \
        t0       = pk_fma_shi(A.x,  v01, t0);                                  \
        t0       = pk_fma_slo(A.y,  v02, t0);                                  \
        f32x2 t1 = pk_mul_shi(A.y,  v10);                                      \
        t1       = pk_fma_slo(Bq.x, v11, t1);                                  \
        t1       = pk_fma_shi(Bq.x, v12, t1);                                  \
        f32x2 t2 = pk_mul_slo(Bq.y, v20);                                      \
        t2       = pk_fma_shi(Bq.y, v21, t2);                                  \
        t2       = pk_fma_slo(Cq.x, v22, t2);                                  \
        f32x2 s_ = pk_add_vv(t0, t1);                                          \
        s_       = pk_add_vv(s_, t2);                                          \
        s_       = pk_add_shi(Cq.x, s_);                                       \
        acc.x = fmaxf(acc.x, s_.x);                                            \
        acc.y = fmaxf(acc.y, s_.y);                                            \
    } while (0)

#define GRP8(G, CW)                                                            \
    ENT((G)*8+0, CW, 0); ENT((G)*8+1, CW, 1); ENT((G)*8+2, CW, 2);             \
    ENT((G)*8+3, CW, 3); ENT((G)*8+4, CW, 4); ENT((G)*8+5, CW, 5);             \
    ENT((G)*8+6, CW, 6); ENT((G)*8+7, CW, 7);

    GRP8(0, cw0) GRP8(1, cw1) GRP8(2, cw2) GRP8(3, cw3)
    GRP8(4, cw4) GRP8(5, cw5) GRP8(6, cw6) GRP8(7, cw7)

#undef GRP8
#undef ENT
#undef NBLOAD

    if (lanev) {
        const size_t o = (((size_t)b * OUT_CH + oc) * HH + (r0 + grp * 2)) * WW + tx;
        out[o]      = acc.x;   // row grp*2
        out[o + WW] = acc.y;   // row grp*2 + 1
    }
}

// ---------------- fallback (R13-style): in-block sort + LDS weight table ----------------
#define LDSROWS  (TILEROWS + 2)
#define LROW     56
#define LDS_XN   (IN_CH * LDSROWS * LROW)
#define NVEC     (IN_CH * LDSROWS * 14)

__global__ __launch_bounds__(256, 2)
void rptn_fused_fallback(const float* __restrict__ x,
                         const float* __restrict__ w,
                         const float* __restrict__ bias,
                         const int*   __restrict__ idx,
                         float*       __restrict__ out) {
    const int oc   = blockIdx.x;
    const int tile = blockIdx.y;
    const int b    = blockIdx.z;
    const int tid  = threadIdx.x;
    const int tx   = tid & 63;
    const int grp  = __builtin_amdgcn_readfirstlane(tid >> 6);

    __shared__ float s_x[LDS_XN];
    __shared__ f32x4 s_w[SET_LEN * 3];
    __shared__ int   s_cnt[IN_CH];
    __shared__ int   s_pos[IN_CH];
    __shared__ int   s_eord[SET_LEN];

    if (tid < IN_CH) s_cnt[tid] = 0;
    __syncthreads();
    int my_e = 0;
    if (tid < SET_LEN) {
        my_e = idx[oc * SET_LEN + tid];
        atomicAdd(&s_cnt[my_e >> 8], 1);
    }
    __syncthreads();
    if (tid == 0) {
        int run = 0;
        for (int c = 0; c < IN_CH; ++c) { s_pos[c] = run; run += s_cnt[c]; }
    }
    __syncthreads();
    if (tid < SET_LEN) {
        int p = atomicAdd(&s_pos[my_e >> 8], 1);
        s_eord[p] = my_e;
    }
    __syncthreads();

    float* s_wf = (float*)s_w;
    for (int i = tid; i < SET_LEN * 12; i += 256) {
        const int j    = i / 12;
        const int comp = i - j * 12;
        const int e    = s_eord[j];
        float v;
        if (comp < 9)        v = w[e * 9 + comp];
        else if (comp == 9)  v = bias[e];
        else if (comp == 10) v = __int_as_float(e >> 8);
        else                 v = 0.0f;
        s_wf[j * 12 + comp] = v;
    }

    const int r0 = tile * TILEROWS;
    const float* xb = x + (size_t)b * IN_CH * HH * WW;
    #pragma unroll
    for (int it = 0; it < 9; ++it) {
        const int v = tid + it * 256;
        if (it < 8 || v < NVEC) {
            const int c   = v / (LDSROWS * 14);
            const int rem = v - c * (LDSROWS * 14);
            const int r   = rem / 14;
            const int q   = rem - r * 14;
            const int gr  = r0 - 1 + r;
            f32x4 val = {0, 0, 0, 0};
            if ((unsigned)gr < (unsigned)HH)
                val = *(const f32x4*)(xb + (c * HH + gr) * WW + q * 4);
            *(f32x4*)&s_x[(c * LDSROWS + r) * LROW + q * 4] = val;
        }
    }
    __syncthreads();

    const bool  lanev = (tx < WW);
    const int   txr   = lanev ? tx : 0;
    const int   txl   = (txr > 0)  ? txr - 1 : 0;
    const int   txp   = (txr < 55) ? txr + 1 : 55;
    const float lm    = (txr == 0)  ? 0.0f : 1.0f;
    const float rm    = (txr == 55) ? 0.0f : 1.0f;

    f32x2 acc = { -__builtin_inff(), -__builtin_inff() };
    int ccur = -1;
    f32x2 v00={0,0},v01={0,0},v02={0,0};
    f32x2 v10={0,0},v11={0,0},v12={0,0};
    f32x2 v20={0,0},v21={0,0},v22={0,0};

    #pragma unroll 2
    for (int k = 0; k < SET_LEN; ++k) {
        const f32x4 q0 = s_w[k * 3 + 0];
        const f32x4 q1 = s_w[k * 3 + 1];
        const f32x4 q2 = s_w[k * 3 + 2];
        const int c = __float_as_int(q2.z);
        if (c != ccur) {
            ccur = c;
            const float* sp = &s_x[(c * LDSROWS + grp * 2) * LROW];
            const float n00=sp[txl]*lm,        n01=sp[txr],        n02=sp[txp]*rm;
            const float n10=sp[LROW+txl]*lm,   n11=sp[LROW+txr],   n12=sp[LROW+txp]*rm;
            const float n20=sp[2*LROW+txl]*lm, n21=sp[2*LROW+txr], n22=sp[2*LROW+txp]*rm;
            const float n30=sp[3*LROW+txl]*lm, n31=sp[3*LROW+txr], n32=sp[3*LROW+txp]*rm;
            v00=(f32x2){n00,n10}; v01=(f32x2){n01,n11}; v02=(f32x2){n02,n12};
            v10=(f32x2){n10,n20}; v11=(f32x2){n11,n21}; v12=(f32x2){n12,n22};
            v20=(f32x2){n20,n30}; v21=(f32x2){n21,n31}; v22=(f32x2){n22,n32};
        }
        f32x2 t0 = __builtin_elementwise_fma(splat2(q0.z), v02,
                   __builtin_elementwise_fma(splat2(q0.y), v01,
                   __builtin_elementwise_fma(splat2(q0.x), v00, splat2(q2.y))));
        f32x2 t1 = __builtin_elementwise_fma(splat2(q1.y), v12,
                   __builtin_elementwise_fma(splat2(q1.x), v11,
                                             splat2(q0.w) * v10));
        f32x2 t2 = __builtin_elementwise_fma(splat2(q2.x), v22,
                   __builtin_elementwise_fma(splat2(q1.w), v21,
                                             splat2(q1.z) * v20));
        const f32x2 s = t0 + (t1 + t2);
        acc.x = fmaxf(acc.x, s.x);
        acc.y = fmaxf(acc.y, s.y);
    }

    if (lanev) {
        const size_t o = (((size_t)b * OUT_CH + oc) * HH + (r0 + grp * 2)) * WW + tx;
        out[o]      = acc.x;
        out[o + WW] = acc.y;
    }
}

extern "C" void kernel_launch(void* const* d_in, const int* in_sizes, int n_in,
                              void* d_out, int out_size, void* d_ws, size_t ws_size,
                              hipStream_t stream) {
    const float* x    = (const float*)d_in[0];
    const float* w    = (const float*)d_in[1];
    const float* bias = (const float*)d_in[2];
    const int*   idx  = (const int*)d_in[3];
    float*       out  = (float*)d_out;

    dim3 grid(OUT_CH, NTILES, BB);   // oc fastest -> x rows L2-resident across oc

    if (ws_size >= (size_t)WS_NEEDED) {
        unsigned* ws_cw = (unsigned*)((char*)d_ws + WS_CW_OFF);
        float*    ws_w  = (float*)((char*)d_ws + WS_W_OFF);
        rptn_presort<<<dim3(OUT_CH), dim3(64), 0, stream>>>(w, bias, idx, ws_cw, ws_w);
        rptn_fused_kernel<<<grid, dim3(256), 0, stream>>>(x, ws_cw, ws_w, out);
    } else {
        rptn_fused_fallback<<<grid, dim3(256), 0, stream>>>(x, w, bias, idx, out);
    }
}

// Round 17
// 132.465 us; speedup vs baseline: 1.2563x; 1.0445x over previous
//
#include <hip/hip_runtime.h>

#define IN_CH    16
#define OUT_CH   64
#define SET_LEN  64
#define BB       8
#define HH       56
#define WW       56

#define TILEROWS 8              // output rows per block (56 = 7*8)
#define NTILES   7
#define LDSROWS  (TILEROWS + 2) // staged rows incl. halo
#define LROW     56             // exactly the data columns; 224B row stride
#define LDS_XN   (IN_CH * LDSROWS * LROW)   // 8960 floats = 35840 B
#define NVEC     (IN_CH * LDSROWS * 14)     // 2240 float4 transfers

// ws layout: [0,2048): packed channel words (8 u32/oc); [2048,+192K): weight records
#define WS_CW_OFF 0
#define WS_W_OFF  2048
#define WS_NEEDED (WS_W_OFF + OUT_CH * SET_LEN * 12 * 4)   // 198656 B

typedef float f32x2 __attribute__((ext_vector_type(2)));
typedef float f32x4 __attribute__((ext_vector_type(4)));

static __device__ __forceinline__ f32x2 splat2(float s) { return (f32x2){s, s}; }

// ---- packed-fp32 VOP3P helpers: SGPR-pair half broadcast to both lanes ----
static __device__ __forceinline__ f32x2 pk_mul_slo(unsigned long long sp, f32x2 b) {
    f32x2 d;
    asm("v_pk_mul_f32 %0, %1, %2 op_sel:[0,0] op_sel_hi:[0,1]"
        : "=v"(d) : "s"(sp), "v"(b));
    return d;
}
static __device__ __forceinline__ f32x2 pk_mul_shi(unsigned long long sp, f32x2 b) {
    f32x2 d;
    asm("v_pk_mul_f32 %0, %1, %2 op_sel:[1,0] op_sel_hi:[1,1]"
        : "=v"(d) : "s"(sp), "v"(b));
    return d;
}
static __device__ __forceinline__ f32x2 pk_fma_slo(unsigned long long sp, f32x2 b, f32x2 c) {
    f32x2 d;
    asm("v_pk_fma_f32 %0, %1, %2, %3 op_sel:[0,0,0] op_sel_hi:[0,1,1]"
        : "=v"(d) : "s"(sp), "v"(b), "v"(c));
    return d;
}
static __device__ __forceinline__ f32x2 pk_fma_shi(unsigned long long sp, f32x2 b, f32x2 c) {
    f32x2 d;
    asm("v_pk_fma_f32 %0, %1, %2, %3 op_sel:[1,0,0] op_sel_hi:[1,1,1]"
        : "=v"(d) : "s"(sp), "v"(b), "v"(c));
    return d;
}
static __device__ __forceinline__ f32x2 pk_add_vv(f32x2 a, f32x2 b) {
    f32x2 d;
    asm("v_pk_add_f32 %0, %1, %2 op_sel:[0,0] op_sel_hi:[1,1]"
        : "=v"(d) : "v"(a), "v"(b));
    return d;
}
static __device__ __forceinline__ f32x2 pk_add_shi(unsigned long long sp, f32x2 b) {
    f32x2 d;
    asm("v_pk_add_f32 %0, %1, %2 op_sel:[1,0] op_sel_hi:[1,1]"
        : "=v"(d) : "s"(sp), "v"(b));
    return d;
}

// ---------------- pre-kernel: per-oc counting sort + weight gather + chan words ----
// record per entry (12 floats, 48B): w0..w8, bias, chan(bits), pad
__global__ __launch_bounds__(64)
void rptn_presort(const float* __restrict__ w, const float* __restrict__ bias,
                  const int* __restrict__ idx, unsigned* __restrict__ ws_cw,
                  float* __restrict__ ws_w) {
    const int oc = blockIdx.x;
    const int t  = threadIdx.x;
    __shared__ int cnt[IN_CH], pos[IN_CH], eord[SET_LEN];

    if (t < IN_CH) cnt[t] = 0;
    __syncthreads();
    const int e = idx[oc * SET_LEN + t];
    const int c = e >> 8;
    atomicAdd(&cnt[c], 1);
    __syncthreads();
    if (t == 0) {
        int run = 0;
        for (int i = 0; i < IN_CH; ++i) { pos[i] = run; run += cnt[i]; }
    }
    __syncthreads();
    const int p = atomicAdd(&pos[c], 1);
    eord[p] = e;
    __syncthreads();

    const int    es  = eord[t];
    float*       dst = ws_w + ((size_t)oc * SET_LEN + t) * 12;
    const float* src = w + es * 9;
    #pragma unroll
    for (int i = 0; i < 9; ++i) dst[i] = src[i];
    dst[9]  = bias[es];
    dst[10] = __int_as_float(es >> 8);
    dst[11] = 0.0f;

    if (t < 8) {                     // pack 8 sorted channel ids per u32
        unsigned wd = 0;
        #pragma unroll
        for (int j = 0; j < 8; ++j)
            wd |= ((unsigned)(eord[t * 8 + j] >> 8)) << (4 * j);
        ws_cw[oc * 8 + t] = wd;
    }
}

// ---- main fused kernel: LDS x-tile + SMEM weights + SALU channel ids + pk math ----
__global__ __launch_bounds__(256, 4)
void rptn_fused_kernel(const float* __restrict__ x,
                       const unsigned* __restrict__ ws_cw,
                       const float* __restrict__ ws_w,
                       float*       __restrict__ out) {
    const int oc   = blockIdx.x;   // fastest-varying -> x tile reused across oc in L2
    const int tile = blockIdx.y;
    const int b    = blockIdx.z;
    const int tid  = threadIdx.x;
    const int tx   = tid & 63;
    const int grp  = __builtin_amdgcn_readfirstlane(tid >> 6); // wave-uniform

    __shared__ float s_x[LDS_XN];

    // ---- stage x tile: aligned vec4 loads + vec4 LDS writes, fully pipelined ----
    const int r0 = tile * TILEROWS;
    const float* xb = x + (size_t)b * IN_CH * HH * WW;
    #pragma unroll
    for (int it = 0; it < 9; ++it) {
        const int v = tid + it * 256;
        if (it < 8 || v < NVEC) {                  // last round: tid<192
            const int c   = v / (LDSROWS * 14);
            const int rem = v - c * (LDSROWS * 14);
            const int r   = rem / 14;
            const int q   = rem - r * 14;
            const int gr  = r0 - 1 + r;
            f32x4 val = {0, 0, 0, 0};
            if ((unsigned)gr < (unsigned)HH)
                val = *(const f32x4*)(xb + (c * HH + gr) * WW + q * 4);
            *(f32x4*)&s_x[(c * LDSROWS + r) * LROW + q * 4] = val;
        }
    }

    // channel words: uniform s_load once -> pure SALU branch thereafter
    const unsigned* cwp = ws_cw + oc * 8;
    const unsigned cw0 = cwp[0], cw1 = cwp[1], cw2 = cwp[2], cw3 = cwp[3];
    const unsigned cw4 = cwp[4], cw5 = cwp[5], cw6 = cwp[6], cw7 = cwp[7];

    // weight records: uniform -> s_load_dwordx4 with immediate offsets (affine in k)
    const ulonglong2* wt = (const ulonglong2*)ws_w + (size_t)oc * SET_LEN * 3;

    __syncthreads();

    // ---- fused conv + bias + running max; 2 rows per lane, packed fp32 ----
    const bool  lanev = (tx < WW);
    const int   txr   = lanev ? tx : 0;            // clamp for safe LDS reads
    const int   txl   = (txr > 0)  ? txr - 1 : 0;  // masked by lm
    const int   txp   = (txr < 55) ? txr + 1 : 55; // masked by rm
    const float lm    = (txr == 0)  ? 0.0f : 1.0f;
    const float rm    = (txr == 55) ? 0.0f : 1.0f;

    f32x2 acc = { -__builtin_inff(), -__builtin_inff() };
    int ccur = -1;
    f32x2 v00={0,0},v01={0,0},v02={0,0};
    f32x2 v10={0,0},v11={0,0},v12={0,0};
    f32x2 v20={0,0},v21={0,0},v22={0,0};

#define NBLOAD(C_) do {                                                        \
        const float* sp = &s_x[((C_) * LDSROWS + grp * 2) * LROW];             \
        const float n00=sp[txl]*lm,        n01=sp[txr],        n02=sp[txp]*rm; \
        const float n10=sp[LROW+txl]*lm,   n11=sp[LROW+txr],   n12=sp[LROW+txp]*rm; \
        const float n20=sp[2*LROW+txl]*lm, n21=sp[2*LROW+txr], n22=sp[2*LROW+txp]*rm; \
        const float n30=sp[3*LROW+txl]*lm, n31=sp[3*LROW+txr], n32=sp[3*LROW+txp]*rm; \
        v00=(f32x2){n00,n10}; v01=(f32x2){n01,n11}; v02=(f32x2){n02,n12};      \
        v10=(f32x2){n10,n20}; v11=(f32x2){n11,n21}; v12=(f32x2){n12,n22};      \
        v20=(f32x2){n20,n30}; v21=(f32x2){n21,n31}; v22=(f32x2){n22,n32};      \
    } while (0)

#define ENT(K, CW, J) do {                                                     \
        const int c_ = (int)(((CW) >> (4 * (J))) & 15u);   /* pure SALU */     \
        if (c_ != ccur) { ccur = c_; NBLOAD(c_); }                             \
        const ulonglong2 A  = wt[(K) * 3 + 0];  /* {w0w1, w2w3}  s_load x4 */  \
        const ulonglong2 Bq = wt[(K) * 3 + 1];  /* {w4w5, w6w7} */             \
        const ulonglong2 Cq = wt[(K) * 3 + 2];  /* {w8·bias, chan·pad} */      \
        f32x2 t0 = pk_mul_slo(A.x,  v00);                                      \
        t0       = pk_fma_shi(A.x,  v01, t0);                                  \
        t0       = pk_fma_slo(A.y,  v02, t0);                                  \
        f32x2 t1 = pk_mul_shi(A.y,  v10);                                      \
        t1       = pk_fma_slo(Bq.x, v11, t1);                                  \
        t1       = pk_fma_shi(Bq.x, v12, t1);                                  \
        f32x2 t2 = pk_mul_slo(Bq.y, v20);                                      \
        t2       = pk_fma_shi(Bq.y, v21, t2);                                  \
        t2       = pk_fma_slo(Cq.x, v22, t2);                                  \
        f32x2 s_ = pk_add_vv(t0, t1);                                          \
        s_       = pk_add_vv(s_, t2);                                          \
        s_       = pk_add_shi(Cq.x, s_);       /* + bias */                    \
        acc.x = fmaxf(acc.x, s_.x);                                            \
        acc.y = fmaxf(acc.y, s_.y);                                            \
    } while (0)

#define GRP8(G, CW)                                                            \
    ENT((G)*8+0, CW, 0); ENT((G)*8+1, CW, 1); ENT((G)*8+2, CW, 2);             \
    ENT((G)*8+3, CW, 3); ENT((G)*8+4, CW, 4); ENT((G)*8+5, CW, 5);             \
    ENT((G)*8+6, CW, 6); ENT((G)*8+7, CW, 7);

    GRP8(0, cw0) GRP8(1, cw1) GRP8(2, cw2) GRP8(3, cw3)
    GRP8(4, cw4) GRP8(5, cw5) GRP8(6, cw6) GRP8(7, cw7)

#undef GRP8
#undef ENT
#undef NBLOAD

    if (lanev) {
        const size_t o = (((size_t)b * OUT_CH + oc) * HH + (r0 + grp * 2)) * WW + tx;
        out[o]      = acc.x;   // row grp*2
        out[o + WW] = acc.y;   // row grp*2 + 1
    }
}

// ---------------- fallback (R13-style): in-block sort + LDS weight table ----------------
__global__ __launch_bounds__(256, 2)
void rptn_fused_fallback(const float* __restrict__ x,
                         const float* __restrict__ w,
                         const float* __restrict__ bias,
                         const int*   __restrict__ idx,
                         float*       __restrict__ out) {
    const int oc   = blockIdx.x;
    const int tile = blockIdx.y;
    const int b    = blockIdx.z;
    const int tid  = threadIdx.x;
    const int tx   = tid & 63;
    const int grp  = __builtin_amdgcn_readfirstlane(tid >> 6);

    __shared__ float s_x[LDS_XN];
    __shared__ f32x4 s_w[SET_LEN * 3];
    __shared__ int   s_cnt[IN_CH];
    __shared__ int   s_pos[IN_CH];
    __shared__ int   s_eord[SET_LEN];

    if (tid < IN_CH) s_cnt[tid] = 0;
    __syncthreads();
    int my_e = 0;
    if (tid < SET_LEN) {
        my_e = idx[oc * SET_LEN + tid];
        atomicAdd(&s_cnt[my_e >> 8], 1);
    }
    __syncthreads();
    if (tid == 0) {
        int run = 0;
        for (int c = 0; c < IN_CH; ++c) { s_pos[c] = run; run += s_cnt[c]; }
    }
    __syncthreads();
    if (tid < SET_LEN) {
        int p = atomicAdd(&s_pos[my_e >> 8], 1);
        s_eord[p] = my_e;
    }
    __syncthreads();

    float* s_wf = (float*)s_w;
    for (int i = tid; i < SET_LEN * 12; i += 256) {
        const int j    = i / 12;
        const int comp = i - j * 12;
        const int e    = s_eord[j];
        float v;
        if (comp < 9)        v = w[e * 9 + comp];
        else if (comp == 9)  v = bias[e];
        else if (comp == 10) v = __int_as_float(e >> 8);
        else                 v = 0.0f;
        s_wf[j * 12 + comp] = v;
    }

    const int r0 = tile * TILEROWS;
    const float* xb = x + (size_t)b * IN_CH * HH * WW;
    #pragma unroll
    for (int it = 0; it < 9; ++it) {
        const int v = tid + it * 256;
        if (it < 8 || v < NVEC) {
            const int c   = v / (LDSROWS * 14);
            const int rem = v - c * (LDSROWS * 14);
            const int r   = rem / 14;
            const int q   = rem - r * 14;
            const int gr  = r0 - 1 + r;
            f32x4 val = {0, 0, 0, 0};
            if ((unsigned)gr < (unsigned)HH)
                val = *(const f32x4*)(xb + (c * HH + gr) * WW + q * 4);
            *(f32x4*)&s_x[(c * LDSROWS + r) * LROW + q * 4] = val;
        }
    }
    __syncthreads();

    const bool  lanev = (tx < WW);
    const int   txr   = lanev ? tx : 0;
    const int   txl   = (txr > 0)  ? txr - 1 : 0;
    const int   txp   = (txr < 55) ? txr + 1 : 55;
    const float lm    = (txr == 0)  ? 0.0f : 1.0f;
    const float rm    = (txr == 55) ? 0.0f : 1.0f;

    f32x2 acc = { -__builtin_inff(), -__builtin_inff() };
    int ccur = -1;
    f32x2 v00={0,0},v01={0,0},v02={0,0};
    f32x2 v10={0,0},v11={0,0},v12={0,0};
    f32x2 v20={0,0},v21={0,0},v22={0,0};

    #pragma unroll 2
    for (int k = 0; k < SET_LEN; ++k) {
        const f32x4 q0 = s_w[k * 3 + 0];
        const f32x4 q1 = s_w[k * 3 + 1];
        const f32x4 q2 = s_w[k * 3 + 2];
        const int c = __float_as_int(q2.z);
        if (c != ccur) {
            ccur = c;
            const float* sp = &s_x[(c * LDSROWS + grp * 2) * LROW];
            const float n00=sp[txl]*lm,        n01=sp[txr],        n02=sp[txp]*rm;
            const float n10=sp[LROW+txl]*lm,   n11=sp[LROW+txr],   n12=sp[LROW+txp]*rm;
            const float n20=sp[2*LROW+txl]*lm, n21=sp[2*LROW+txr], n22=sp[2*LROW+txp]*rm;
            const float n30=sp[3*LROW+txl]*lm, n31=sp[3*LROW+txr], n32=sp[3*LROW+txp]*rm;
            v00=(f32x2){n00,n10}; v01=(f32x2){n01,n11}; v02=(f32x2){n02,n12};
            v10=(f32x2){n10,n20}; v11=(f32x2){n11,n21}; v12=(f32x2){n12,n22};
            v20=(f32x2){n20,n30}; v21=(f32x2){n21,n31}; v22=(f32x2){n22,n32};
        }
        f32x2 t0 = __builtin_elementwise_fma(splat2(q0.z), v02,
                   __builtin_elementwise_fma(splat2(q0.y), v01,
                   __builtin_elementwise_fma(splat2(q0.x), v00, splat2(q2.y))));
        f32x2 t1 = __builtin_elementwise_fma(splat2(q1.y), v12,
                   __builtin_elementwise_fma(splat2(q1.x), v11,
                                             splat2(q0.w) * v10));
        f32x2 t2 = __builtin_elementwise_fma(splat2(q2.x), v22,
                   __builtin_elementwise_fma(splat2(q1.w), v21,
                                             splat2(q1.z) * v20));
        const f32x2 s = t0 + (t1 + t2);
        acc.x = fmaxf(acc.x, s.x);
        acc.y = fmaxf(acc.y, s.y);
    }

    if (lanev) {
        const size_t o = (((size_t)b * OUT_CH + oc) * HH + (r0 + grp * 2)) * WW + tx;
        out[o]      = acc.x;
        out[o + WW] = acc.y;
    }
}

extern "C" void kernel_launch(void* const* d_in, const int* in_sizes, int n_in,
                              void* d_out, int out_size, void* d_ws, size_t ws_size,
                              hipStream_t stream) {
    const float* x    = (const float*)d_in[0];
    const float* w    = (const float*)d_in[1];
    const float* bias = (const float*)d_in[2];
    const int*   idx  = (const int*)d_in[3];
    float*       out  = (float*)d_out;

    dim3 grid(OUT_CH, NTILES, BB);   // oc fastest -> x tile L2 reuse

    if (ws_size >= (size_t)WS_NEEDED) {
        unsigned* ws_cw = (unsigned*)((char*)d_ws + WS_CW_OFF);
        float*    ws_w  = (float*)((char*)d_ws + WS_W_OFF);
        rptn_presort<<<dim3(OUT_CH), dim3(64), 0, stream>>>(w, bias, idx, ws_cw, ws_w);
        rptn_fused_kernel<<<grid, dim3(256), 0, stream>>>(x, ws_cw, ws_w, out);
    } else {
        rptn_fused_fallback<<<grid, dim3(256), 0, stream>>>(x, w, bias, idx, out);
    }
}